// Round 12
// baseline (820.482 us; speedup 1.0000x reference)
//
#include <hip/hip_runtime.h>

#define HID 64
#define IN_CH 128
#define NEG_SLOPE 0.2f
#define LN_EPS 1e-5f
#define SCAN_B 256
#define CAP 48
#define NPSB 128          // nodes per bin (power of 2: bin = d >> 7)
#define EPB 1024          // edges per partition block

typedef float f32x4 __attribute__((ext_vector_type(4)));
typedef short s16x8 __attribute__((ext_vector_type(8)));
typedef unsigned long long ull;

__device__ __forceinline__ ushort f2b(float f) {
    uint u = __float_as_uint(f);
    uint r = (u + 0x7fffu + ((u >> 16) & 1u)) >> 16;
    return (ushort)r;
}
__device__ __forceinline__ float b2f(ushort u) {
    return __uint_as_float((uint)u << 16);
}
__device__ __forceinline__ float lrelu_exp(float v) {
    v = (v > 0.f) ? v : NEG_SLOPE * v;
    return __expf(v);
}
__device__ __forceinline__ uint pack_rec(int s, float w) {
    return ((uint)s << 15) | (f2b(w) & 0x7fffu);
}

// ---------------------------------------------------------------------------
// K1: h = bf16(x) @ bf16(W) via MFMA 16x16x32. 64 nodes/block, 4 waves.
// ---------------------------------------------------------------------------
__global__ __launch_bounds__(256) void k_linear_mfma(
        const float* __restrict__ x, const float* __restrict__ W,
        const float* __restrict__ att_src, const float* __restrict__ att_dst,
        ushort* __restrict__ hb, float* __restrict__ asrc, float* __restrict__ adst,
        int n_nodes) {
    __shared__ ushort xs[64 * 128];
    __shared__ ushort wt[64 * 128];
    int t = threadIdx.x;
    int base = blockIdx.x * 64;

    for (int j = 0; j < 32; ++j) {
        int f = t + j * 256;
        int k = f >> 6, c = f & 63;
        wt[(c * 128 + k) ^ ((c & 7) << 3)] = f2b(W[f]);
    }
    const float4* xv = (const float4*)(x + (size_t)base * IN_CH);
    for (int j = 0; j < 8; ++j) {
        int f = t + j * 256;
        int row = f >> 5;
        int kq = f & 31;
        float4 v = make_float4(0.f, 0.f, 0.f, 0.f);
        if (base + row < n_nodes) v = xv[f];
        int off = (row * 128 + kq * 4) ^ ((row & 7) << 3);
        ushort4 b;
        b.x = f2b(v.x); b.y = f2b(v.y); b.z = f2b(v.z); b.w = f2b(v.w);
        *(ushort4*)&xs[off] = b;
    }
    __syncthreads();

    int wv = t >> 6;
    int lane = t & 63;
    int r16 = lane & 15, hi = lane >> 4;

    f32x4 acc[4] = {{0,0,0,0},{0,0,0,0},{0,0,0,0},{0,0,0,0}};
#pragma unroll
    for (int kk = 0; kk < 4; ++kk) {
        int ka = kk * 32 + hi * 8;
        int arow = wv * 16 + r16;
        s16x8 afrag = *(const s16x8*)&xs[(arow * 128 + ka) ^ ((arow & 7) << 3)];
#pragma unroll
        for (int n = 0; n < 4; ++n) {
            int brow = n * 16 + r16;
            s16x8 bfrag = *(const s16x8*)&wt[(brow * 128 + ka) ^ ((brow & 7) << 3)];
            acc[n] = __builtin_amdgcn_mfma_f32_16x16x32_bf16(afrag, bfrag, acc[n], 0, 0, 0);
        }
    }

    float avs[4], avd[4];
#pragma unroll
    for (int n = 0; n < 4; ++n) {
        avs[n] = att_src[n * 16 + r16];
        avd[n] = att_dst[n * 16 + r16];
    }
#pragma unroll
    for (int r = 0; r < 4; ++r) {
        int node = base + wv * 16 + hi * 4 + r;
        bool ok = node < n_nodes;
        float sp = 0.f, dp = 0.f;
#pragma unroll
        for (int n = 0; n < 4; ++n) {
            float v = acc[n][r];
            if (ok) hb[(size_t)node * HID + n * 16 + r16] = f2b(v);
            sp = fmaf(v, avs[n], sp);
            dp = fmaf(v, avd[n], dp);
        }
#pragma unroll
        for (int m = 1; m <= 8; m <<= 1) {
            sp += __shfl_xor(sp, m, 64);
            dp += __shfl_xor(dp, m, 64);
        }
        if (ok && r16 == 0) { asrc[node] = sp; adst[node] = dp; }
    }
}

// ---------------------------------------------------------------------------
// K2a: per-block histogram over NB bins (bin = d >> 7) via LDS atomics.
// hist[block*NB + bin] = count (coalesced row write).
// ---------------------------------------------------------------------------
__global__ __launch_bounds__(256) void k_hist(
        const int* __restrict__ ei_dst, int n_edges, int NB,
        uint* __restrict__ hist) {
    extern __shared__ uint hcnt[];
    int tid = threadIdx.x;
    for (int j = tid; j < NB; j += 256) hcnt[j] = 0;
    __syncthreads();

    int e0 = blockIdx.x * EPB;
    int e1 = min(e0 + EPB, n_edges);
    for (int e = e0 + tid; e < e1; e += 256) {
        uint b = (uint)__builtin_nontemporal_load(ei_dst + e) >> 7;
        atomicAdd(&hcnt[b], 1u);
    }
    __syncthreads();
    uint* row = hist + (size_t)blockIdx.x * NB;
    for (int j = tid; j < NB; j += 256) row[j] = hcnt[j];
}

// ---------------------------------------------------------------------------
// K2b: per-bin column scan (one wave per bin) over nblocks. In place:
// hist[i*NB+b] -> exclusive within-bin offset of block i; totals[b] = sum.
// ---------------------------------------------------------------------------
__global__ __launch_bounds__(512) void k_scanA(
        uint* __restrict__ hist, int nblocks, int NB, uint* __restrict__ totals) {
    int b = blockIdx.x * 8 + (threadIdx.x >> 6);
    if (b >= NB) return;
    int lane = threadIdx.x & 63;
    uint running = 0;
    for (int i0 = 0; i0 < nblocks; i0 += 64) {
        int i = i0 + lane;
        uint v = (i < nblocks) ? hist[(size_t)i * NB + b] : 0;
        uint orig = v;
#pragma unroll
        for (int off = 1; off < 64; off <<= 1) {
            uint n = __shfl_up(v, off, 64);
            if (lane >= off) v += n;
        }
        if (i < nblocks) hist[(size_t)i * NB + b] = running + v - orig;
        running += (uint)__shfl((int)v, 63, 64);
    }
    if (lane == 0) totals[b] = running;
}

// ---------------------------------------------------------------------------
// K2c: exclusive scan of totals -> binbase[NB+1]. Single block, 1024 threads.
// ---------------------------------------------------------------------------
__global__ __launch_bounds__(1024) void k_scanB(
        const uint* __restrict__ totals, int NB, uint* __restrict__ binbase) {
    __shared__ uint tmp[1024];
    int t = threadIdx.x;
    uint v = (t < NB) ? totals[t] : 0;
    tmp[t] = v;
    __syncthreads();
    for (int off = 1; off < 1024; off <<= 1) {
        uint a = (t >= off) ? tmp[t - off] : 0;
        __syncthreads();
        tmp[t] += a;
        __syncthreads();
    }
    if (t < NB) binbase[t] = tmp[t] - v;
    if (t == NB - 1) binbase[NB] = tmp[t];
}

// ---------------------------------------------------------------------------
// K2d: placement. LDS cursors = binbase[b] + own block's within-bin offset.
// No global atomics; 8B fire-and-forget scattered stores.
// rec64 = d:hi32 | (s<<15 | bf16w):lo32
// ---------------------------------------------------------------------------
__global__ __launch_bounds__(256) void k_place(
        const int* __restrict__ ei, int n_edges,
        const float* __restrict__ asrc, const float* __restrict__ adst,
        int NB, const uint* __restrict__ hist, const uint* __restrict__ binbase,
        ull* __restrict__ gbuf) {
    extern __shared__ uint cur[];
    int tid = threadIdx.x;
    const uint* row = hist + (size_t)blockIdx.x * NB;
    for (int j = tid; j < NB; j += 256) cur[j] = row[j] + binbase[j];
    __syncthreads();

    int e0 = blockIdx.x * EPB;
    int e1 = min(e0 + EPB, n_edges);
    for (int e = e0 + tid; e < e1; e += 256) {
        int s = __builtin_nontemporal_load(ei + e);
        int d = __builtin_nontemporal_load(ei + n_edges + e);
        float w = lrelu_exp(asrc[s] + adst[d]);
        uint b = (uint)d >> 7;
        uint pos = atomicAdd(&cur[b], 1u);
        gbuf[pos] = ((ull)(uint)d << 32) | pack_rec(s, w);
    }
}

// ---------------------------------------------------------------------------
// K3: fused aggregation. Block b owns nodes [b*128, b*128+128). Reads ONLY
// its own contiguous record slice. 32 lanes per record (element = lane+32m):
// LDS ds_add_f32 at 2-way bank aliasing (free). Epilogue: self loop +
// normalize + bias + LayerNorm + nt store.
// ---------------------------------------------------------------------------
__global__ __launch_bounds__(256) void k_agg(
        const ull* __restrict__ gbuf, const uint* __restrict__ binbase,
        const ushort* __restrict__ hb,
        const float* __restrict__ asrc, const float* __restrict__ adst,
        const float* __restrict__ bias, const float* __restrict__ gamma,
        const float* __restrict__ beta, float* __restrict__ out, int n_nodes) {
    __shared__ float acc[NPSB * 64];
    __shared__ float sumw[NPSB];

    int tid = threadIdx.x;
    int lane = tid & 63;
    int wid = tid >> 6;
    int sl = lane & 31;      // channel pair base
    int g2 = lane >> 5;      // record slot within wave (0/1)

    int lo = blockIdx.x * NPSB;
    int hi = min(lo + NPSB, n_nodes);
    if (lo >= hi) return;
    int nloc = hi - lo;

    for (int i = tid; i < NPSB * 64; i += 256) acc[i] = 0.f;
    if (tid < NPSB) sumw[tid] = 0.f;
    __syncthreads();

    uint rbase = binbase[blockIdx.x];
    uint rcnt = binbase[blockIdx.x + 1] - rbase;
    const ull* buf = gbuf + rbase;

    // 8 records per block-iter (4 waves x 2), unrolled x2 -> 16
    for (uint base = 0; base < rcnt; base += 16) {
        uint i1 = base + (uint)(wid * 2 + g2);
        uint i2 = i1 + 8;
        bool v1 = i1 < rcnt, v2 = i2 < rcnt;
        ull r1 = v1 ? __builtin_nontemporal_load(buf + i1) : 0ull;
        ull r2 = v2 ? __builtin_nontemporal_load(buf + i2) : 0ull;
        if (v1) {
            int d = (int)(r1 >> 32);
            uint lo32 = (uint)r1;
            int s = (int)(lo32 >> 15);
            float w = b2f((ushort)(lo32 & 0x7fffu));
            float ha = b2f(hb[(size_t)s * HID + sl]);
            float hbv = b2f(hb[(size_t)s * HID + sl + 32]);
            int rowo = (d - lo) * 64;
            atomicAdd(&acc[rowo + sl], w * ha);
            atomicAdd(&acc[rowo + sl + 32], w * hbv);
            if (sl == 0) atomicAdd(&sumw[d - lo], w);
        }
        if (v2) {
            int d = (int)(r2 >> 32);
            uint lo32 = (uint)r2;
            int s = (int)(lo32 >> 15);
            float w = b2f((ushort)(lo32 & 0x7fffu));
            float ha = b2f(hb[(size_t)s * HID + sl]);
            float hbv = b2f(hb[(size_t)s * HID + sl + 32]);
            int rowo = (d - lo) * 64;
            atomicAdd(&acc[rowo + sl], w * ha);
            atomicAdd(&acc[rowo + sl + 32], w * hbv);
            if (sl == 0) atomicAdd(&sumw[d - lo], w);
        }
    }
    __syncthreads();

    // epilogue: one wave per node row, lane = channel
    for (int j = wid; j < nloc; j += 4) {
        int node = lo + j;
        float w0 = lrelu_exp(asrc[node] + adst[node]);
        float hv = b2f(hb[(size_t)node * HID + lane]);
        float a = fmaf(w0, hv, acc[j * 64 + lane]);
        float sw = sumw[j] + w0;
        float o = a / sw + bias[lane];

        float msum = o;
#pragma unroll
        for (int msk = 1; msk <= 32; msk <<= 1) msum += __shfl_xor(msum, msk, 64);
        float mu = msum * (1.f / 64.f);
        float dv = o - mu;
        float q = dv * dv;
#pragma unroll
        for (int msk = 1; msk <= 32; msk <<= 1) q += __shfl_xor(q, msk, 64);
        float rst = rsqrtf(q * (1.f / 64.f) + LN_EPS);
        float res = fmaf(dv * rst, gamma[lane], beta[lane]);
        __builtin_nontemporal_store(res, out + (size_t)node * HID + lane);
    }
}

// ---------------------------------------------------------------------------
// Fallback: single-phase fixed-cap fill (round-5 path)
// ---------------------------------------------------------------------------
__global__ void k_fill_cap(const int* __restrict__ ei, int n_edges,
                           const float* __restrict__ asrc, const float* __restrict__ adst,
                           int* __restrict__ deg, uint* __restrict__ edata) {
    int e = blockIdx.x * blockDim.x + threadIdx.x;
    if (e >= n_edges) return;
    int s = ei[e];
    int d = ei[n_edges + e];
    float w = lrelu_exp(asrc[s] + adst[d]);
    int p = atomicAdd(deg + d, 1);
    if (p < CAP) edata[(size_t)d * CAP + p] = pack_rec(s, w);
}

// ---------------------------------------------------------------------------
// Fallback gather + softmax + bias + LayerNorm. 16 lanes/node.
// ---------------------------------------------------------------------------
__global__ __launch_bounds__(256) void k_gather_ln(
        const int* __restrict__ meta, const uint* __restrict__ edata,
        const ushort* __restrict__ hb,
        const float* __restrict__ asrc, const float* __restrict__ adst,
        const float* __restrict__ bias, const float* __restrict__ gamma,
        const float* __restrict__ beta, float* __restrict__ out, int n_nodes) {
    int t = threadIdx.x;
    int grp = t >> 4;
    int sl = t & 15;
    int d = blockIdx.x * 16 + grp;
    if (d >= n_nodes) return;

    int cnt = min(meta[d], CAP);
    const uint* ep = edata + (size_t)d * CAP;

    float v0 = lrelu_exp(asrc[d] + adst[d]);
    ushort4 hv = *(const ushort4*)(hb + (size_t)d * HID + sl * 4);
    float a0 = v0 * b2f(hv.x), a1 = v0 * b2f(hv.y);
    float a2 = v0 * b2f(hv.z), a3 = v0 * b2f(hv.w);
    float sumv = v0;

    for (int i = 0; i < cnt; ++i) {
        uint m0 = ep[i];
        int s0 = m0 >> 15;
        ushort4 h0 = *(const ushort4*)(hb + (size_t)s0 * HID + sl * 4);
        float w0 = b2f((ushort)(m0 & 0x7fffu));
        a0 = fmaf(w0, b2f(h0.x), a0); a1 = fmaf(w0, b2f(h0.y), a1);
        a2 = fmaf(w0, b2f(h0.z), a2); a3 = fmaf(w0, b2f(h0.w), a3);
        sumv += w0;
    }

    float inv = 1.f / sumv;
    const float4 bv = *(const float4*)(bias + sl * 4);
    const float4 gv = *(const float4*)(gamma + sl * 4);
    const float4 btv = *(const float4*)(beta + sl * 4);
    float o0 = fmaf(a0, inv, bv.x), o1 = fmaf(a1, inv, bv.y);
    float o2 = fmaf(a2, inv, bv.z), o3 = fmaf(a3, inv, bv.w);

    float m = o0 + o1 + o2 + o3;
#pragma unroll
    for (int msk = 1; msk <= 8; msk <<= 1) m += __shfl_xor(m, msk, 64);
    float mu = m * (1.f / HID);
    float d0 = o0 - mu, d1 = o1 - mu, d2 = o2 - mu, d3 = o3 - mu;
    float q = d0 * d0 + d1 * d1 + d2 * d2 + d3 * d3;
#pragma unroll
    for (int msk = 1; msk <= 8; msk <<= 1) q += __shfl_xor(q, msk, 64);
    float rst = rsqrtf(q * (1.f / HID) + LN_EPS);

    float4 ov;
    ov.x = fmaf(d0 * rst, gv.x, btv.x);
    ov.y = fmaf(d1 * rst, gv.y, btv.y);
    ov.z = fmaf(d2 * rst, gv.z, btv.z);
    ov.w = fmaf(d3 * rst, gv.w, btv.w);
    *(float4*)(out + (size_t)d * HID + sl * 4) = ov;
}

// ---------------------------------------------------------------------------
extern "C" void kernel_launch(void* const* d_in, const int* in_sizes, int n_in,
                              void* d_out, int out_size, void* d_ws, size_t ws_size,
                              hipStream_t stream) {
    const float* x       = (const float*)d_in[0];
    const int*   ei      = (const int*)  d_in[1];
    const float* W       = (const float*)d_in[2];
    const float* att_src = (const float*)d_in[3];
    const float* att_dst = (const float*)d_in[4];
    const float* bias    = (const float*)d_in[5];
    const float* gamma   = (const float*)d_in[6];
    const float* beta    = (const float*)d_in[7];

    int n_nodes = in_sizes[0] / IN_CH;
    int n_edges = in_sizes[1] / 2;

    float* out = (float*)d_out;

    ushort* hb  = (ushort*)d_ws;                           // n_nodes*HID bf16
    float* asrc = (float*)(hb + (size_t)n_nodes * HID);    // n_nodes
    float* adst = asrc + n_nodes;                          // n_nodes

    int NB = (n_nodes + NPSB - 1) / NPSB;                  // bins (<=1024 for scanB)
    int nblocks_p = (n_edges + EPB - 1) / EPB;

    size_t head_bytes = (size_t)n_nodes * HID * 2 + (size_t)n_nodes * 4 * 2;
    size_t bb_bytes    = ((size_t)(NB + 1) * 4 + 63) & ~(size_t)63;
    size_t tot_bytes   = ((size_t)NB * 4 + 63) & ~(size_t)63;
    size_t hist_bytes  = ((size_t)nblocks_p * NB * 4 + 63) & ~(size_t)63;
    size_t agg_total = head_bytes + 64 + bb_bytes + tot_bytes + hist_bytes
                     + (size_t)n_edges * 8 + 256;

    int* deg = (int*)(adst + n_nodes);
    size_t cap_bytes = head_bytes + (size_t)n_nodes * 4 + (size_t)n_nodes * CAP * 4 + 256;

    k_linear_mfma<<<(n_nodes + 63) / 64, 256, 0, stream>>>(
        x, W, att_src, att_dst, hb, asrc, adst, n_nodes);

    if (NB <= 1024 && ws_size >= agg_total) {
        // ---- atomic-free exact partition: hist -> scanA -> scanB -> place -> agg
        uintptr_t p = (uintptr_t)(adst + n_nodes);
        p = (p + 63) & ~(uintptr_t)63;
        uint* binbase = (uint*)p;                          // NB+1
        uint* totals  = (uint*)(p + bb_bytes);             // NB
        uint* hist    = (uint*)(p + bb_bytes + tot_bytes); // nblocks_p * NB
        uintptr_t gp  = p + bb_bytes + tot_bytes + hist_bytes;
        gp = (gp + 7) & ~(uintptr_t)7;
        ull* gbuf     = (ull*)gp;                          // n_edges

        size_t lds_bins = (size_t)NB * 4;
        k_hist<<<nblocks_p, 256, lds_bins, stream>>>(ei + n_edges, n_edges, NB, hist);
        k_scanA<<<(NB + 7) / 8, 512, 0, stream>>>(hist, nblocks_p, NB, totals);
        k_scanB<<<1, 1024, 0, stream>>>(totals, NB, binbase);
        k_place<<<nblocks_p, 256, lds_bins, stream>>>(ei, n_edges, asrc, adst,
                                                      NB, hist, binbase, gbuf);
        k_agg<<<NB, 256, 0, stream>>>(gbuf, binbase, hb, asrc, adst,
                                      bias, gamma, beta, out, n_nodes);
    } else if (ws_size >= cap_bytes) {
        // ---- single-phase fixed-cap fill (round-5 path) ----
        uint* edata = (uint*)(deg + n_nodes);
        (void)hipMemsetAsync(deg, 0, (size_t)n_nodes * sizeof(int), stream);
        k_fill_cap<<<(n_edges + 255) / 256, 256, 0, stream>>>(
            ei, n_edges, asrc, adst, deg, edata);
        k_gather_ln<<<(n_nodes + 15) / 16, 256, 0, stream>>>(
            deg, edata, hb, asrc, adst, bias, gamma, beta, out, n_nodes);
    }
}